// Round 2
// baseline (652.856 us; speedup 1.0000x reference)
//
#include <hip/hip_runtime.h>

#define NXd 4096
#define NYd 4096
#define Bd  2
#define RROWS 16   // rows per thread-strip; halo overhead Ez=(R+2)/R

// Match reference: compute in double, cast to f32 (jnp.float32(C_MU))
constexpr double DTd   = 1e-11;
constexpr double DXd   = 0.01;
constexpr double EPS0d = 8.854e-12;
constexpr double MU0d  = 4.0 * 3.1415926 * 1e-07;
constexpr float  C_EPS = (float)(DTd / EPS0d / DXd);
constexpr float  C_MU  = (float)(DTd / MU0d / DXd);

// Load 6 Ez values: cols j0-1 .. j0+4 (float4 + 2 cached halo scalars)
__device__ __forceinline__ void load_row6(const float* __restrict__ p, size_t idx,
                                          bool jm_ok, bool jp_ok, float e[6]) {
    float4 v = *(const float4*)(p + idx);
    e[0] = jm_ok ? p[idx - 1] : 0.f;
    e[1] = v.x; e[2] = v.y; e[3] = v.z; e[4] = v.w;
    e[5] = jp_ok ? p[idx + 4] : 0.f;
}

__global__ __launch_bounds__(256) void fdtd_step_kernel(
    const float* __restrict__ Ez, const float* __restrict__ Hx,
    const float* __restrict__ Hy,
    float* __restrict__ EzO, float* __restrict__ HxO, float* __restrict__ HyO)
{
    const int j0 = (blockIdx.x * 256 + threadIdx.x) * 4;  // column start
    const int r0 = blockIdx.y * RROWS;                    // first row of strip
    const int b  = blockIdx.z;

    const bool jm_ok = (j0 > 0);
    const bool jp_ok = (j0 + 4 < NYd);

    const size_t plane = (size_t)b * NXd * NYd + j0;

    // ---- prologue: Ez[r0] and (Ez[r0-1], Hy_new[r0-1]) if they exist
    float ez_c[6], ez_m[6], hynm[4];
    load_row6(Ez, plane + (size_t)r0 * NYd, jm_ok, jp_ok, ez_c);
    if (r0 > 0) {
        const size_t bm = plane + (size_t)(r0 - 1) * NYd;
        load_row6(Ez, bm, jm_ok, jp_ok, ez_m);
        float4 hym = *(const float4*)(Hy + bm);
        float hymv[4] = {hym.x, hym.y, hym.z, hym.w};
#pragma unroll
        for (int k = 0; k < 4; ++k) {
            const bool jn = (j0 + k) < (NYd - 1);
            hynm[k] = jn ? fmaf(C_MU, ez_m[k + 2] - ez_m[k + 1], hymv[k]) : hymv[k];
        }
    } else {
#pragma unroll
        for (int k = 0; k < 4; ++k) hynm[k] = 0.f;   // unused (i==0 -> no Ez update)
    }

    // ---- main strip loop: one new Ez/Hx/Hy row load per iteration
    for (int i = r0; i < r0 + RROWS; ++i) {
        const size_t base = plane + (size_t)i * NYd;
        const bool has_down = (i < NXd - 1);
        const bool has_up   = (i > 0);

        float ez_p[6];
        if (has_down) {
            load_row6(Ez, base + NYd, jm_ok, jp_ok, ez_p);
        } else {
#pragma unroll
            for (int t = 0; t < 6; ++t) ez_p[t] = 0.f;   // unused (no Hx update)
        }

        float4 hxc = *(const float4*)(Hx + base);
        float  hxm1 = jm_ok ? Hx[base - 1] : 0.f;
        float4 hyc = *(const float4*)(Hy + base);
        float hx_[5] = {hxm1, hxc.x, hxc.y, hxc.z, hxc.w};
        float hy_[4] = {hyc.x, hyc.y, hyc.z, hyc.w};

        // Hx_new[i][j0-1 .. j0+3]
        float hxn[5];
#pragma unroll
        for (int t = 0; t < 5; ++t)
            hxn[t] = has_down ? fmaf(-C_MU, ez_p[t] - ez_c[t], hx_[t]) : hx_[t];

        // Hy_new[i][j0..j0+3]
        float hyn[4];
#pragma unroll
        for (int k = 0; k < 4; ++k) {
            const bool jn = (j0 + k) < (NYd - 1);
            hyn[k] = jn ? fmaf(C_MU, ez_c[k + 2] - ez_c[k + 1], hy_[k]) : hy_[k];
        }

        // Ez_new[i][j0..j0+3], uses NEW H values (hynm = Hy_new[i-1])
        float ezn[4];
#pragma unroll
        for (int k = 0; k < 4; ++k) {
            const bool upd = has_up && ((j0 + k) >= 1);
            const float curl = (hyn[k] - hynm[k]) - (hxn[k + 1] - hxn[k]);
            ezn[k] = upd ? fmaf(C_EPS, curl, ez_c[k + 1]) : ez_c[k + 1];
        }

        *(float4*)(EzO + base) = make_float4(ezn[0], ezn[1], ezn[2], ezn[3]);
        *(float4*)(HxO + base) = make_float4(hxn[1], hxn[2], hxn[3], hxn[4]);
        *(float4*)(HyO + base) = make_float4(hyn[0], hyn[1], hyn[2], hyn[3]);

        // ---- roll
#pragma unroll
        for (int t = 0; t < 6; ++t) { ez_m[t] = ez_c[t]; ez_c[t] = ez_p[t]; }
#pragma unroll
        for (int k = 0; k < 4; ++k) hynm[k] = hyn[k];
    }
}

extern "C" void kernel_launch(void* const* d_in, const int* in_sizes, int n_in,
                              void* d_out, int out_size, void* d_ws, size_t ws_size,
                              hipStream_t stream) {
    const float* Ez = (const float*)d_in[0];
    const float* Hx = (const float*)d_in[1];
    const float* Hy = (const float*)d_in[2];
    float* out = (float*)d_out;
    const size_t N = (size_t)Bd * NXd * NYd;

    dim3 grid(NYd / (256 * 4), NXd / RROWS, Bd);   // 4 x 256 x 2 = 2048 blocks
    fdtd_step_kernel<<<grid, dim3(256, 1, 1), 0, stream>>>(
        Ez, Hx, Hy, out, out + N, out + 2 * N);
}